// Round 3
// baseline (3967.324 us; speedup 1.0000x reference)
//
#include <hip/hip_runtime.h>

#define NN 100000
#define NE 640000
#define IND 128
#define HD 256
#define NC 40
#define NPB 32

__device__ __forceinline__ float bf2f(unsigned short u) {
    union { unsigned int i; float f; } c; c.i = ((unsigned int)u) << 16; return c.f;
}
__device__ __forceinline__ unsigned short f2bf(float f) {
    union { float f; unsigned int i; } c; c.f = f;
    unsigned int i = c.i;
    return (unsigned short)((i + 0x7FFFu + ((i >> 16) & 1u)) >> 16); // RNE
}

__global__ void deg_k(const int* __restrict__ dst, float* __restrict__ deg, int E) {
    int g = blockIdx.x * 256 + threadIdx.x;
    if (g < E) atomicAdd(&deg[dst[g]], 1.0f);
}

__global__ void norm_k(float* deg, int N) {
    int g = blockIdx.x * 256 + threadIdx.x;
    if (g < N) deg[g] = rsqrtf(fmaxf(deg[g], 1.0f));
}

// xc[n*C+j] = yc[n*C+j] = feats[n*128 + col0 + j]   (fp32)
__global__ void gather_init_k(const float* __restrict__ feats,
                              float* __restrict__ xc, float* __restrict__ yc,
                              int col0, int logC, int total) {
    int g = blockIdx.x * 256 + threadIdx.x;
    if (g >= total) return;
    const int C = 1 << logC;
    int n = g >> logC, j = g & (C - 1);
    float v = feats[n * IND + col0 + j];
    xc[g] = v; yc[g] = v;
}

// (C/4) threads per edge; each thread: float4 gather + 4 atomics into dst row
__global__ void scatter_k(const float* __restrict__ x, float* __restrict__ xn,
                          const int* __restrict__ src, const int* __restrict__ dst,
                          const float* __restrict__ norm, int E, int logT) {
    int g = blockIdx.x * 256 + threadIdx.x;
    int e = g >> logT;
    if (e >= E) return;
    int c4 = (g & ((1 << logT) - 1)) << 2;
    int C = 4 << logT;
    int s = src[e], d = dst[e];
    float wgt = norm[s] * norm[d];
    const float4 v = *(const float4*)(x + (size_t)s * C + c4);
    float* p = xn + (size_t)d * C + c4;
    atomicAdd(p + 0, v.x * wgt);
    atomicAdd(p + 1, v.y * wgt);
    atomicAdd(p + 2, v.z * wgt);
    atomicAdd(p + 3, v.w * wgt);
}

__global__ void accum_k(float4* __restrict__ y, const float4* __restrict__ xn, int n4) {
    int g = blockIdx.x * 256 + threadIdx.x;
    if (g >= n4) return;
    float4 a = y[g]; const float4 b = xn[g];
    a.x += b.x; a.y += b.y; a.z += b.z; a.w += b.w;
    y[g] = a;
}

// y_out[n*128+col0+j] = yc[n*C+j] * 0.25   (fp32 or bf16 storage)
template <int YBF>
__global__ void store_y_k(const float* __restrict__ yc, void* __restrict__ y,
                          int col0, int logC, int total) {
    int g = blockIdx.x * 256 + threadIdx.x;
    if (g >= total) return;
    const int C = 1 << logC;
    int n = g >> logC, j = g & (C - 1);
    float v = yc[g] * 0.25f; // 1/(K+1)
    if (YBF) ((unsigned short*)y)[n * IND + col0 + j] = f2bf(v);
    else     ((float*)y)[n * IND + col0 + j] = v;
}

// Fused MLP + log_softmax. 32 nodes/block, thread t owns hidden unit t.
template <int YBF>
__global__ __launch_bounds__(256) void mlp_k(
    const void* __restrict__ y, const float* __restrict__ W1,
    const float* __restrict__ B1, const float* __restrict__ W2,
    const float* __restrict__ B2, float* __restrict__ out) {
    __shared__ float y_s[NPB * IND];   // 16 KB
    __shared__ float h_s[NPB * HD];    // 32 KB
    __shared__ float l_s[NPB * NC];    // 5 KB
    const int t = threadIdx.x;
    const int node0 = blockIdx.x * NPB;

    for (int idx = t; idx < NPB * IND; idx += 256) {
        size_t gi = (size_t)node0 * IND + idx;
        y_s[idx] = YBF ? bf2f(((const unsigned short*)y)[gi]) : ((const float*)y)[gi];
    }
    __syncthreads();

    float acc[NPB];
    {
        const float bb = B1[t];
        #pragma unroll
        for (int n = 0; n < NPB; n++) acc[n] = bb;
    }
    for (int i = 0; i < IND; i += 4) {
        const float w0 = W1[(i + 0) * HD + t];
        const float w1 = W1[(i + 1) * HD + t];
        const float w2 = W1[(i + 2) * HD + t];
        const float w3 = W1[(i + 3) * HD + t];
        #pragma unroll
        for (int n = 0; n < NPB; n++) {
            const float4 v = *(const float4*)&y_s[n * IND + i];
            float a = acc[n];
            a = fmaf(v.x, w0, a);
            a = fmaf(v.y, w1, a);
            a = fmaf(v.z, w2, a);
            a = fmaf(v.w, w3, a);
            acc[n] = a;
        }
    }
    #pragma unroll
    for (int n = 0; n < NPB; n++) h_s[n * HD + t] = fmaxf(acc[n], 0.0f);
    __syncthreads();

    // logits: 32*40 = 1280 outputs, 5 per thread
    for (int idx = t; idx < NPB * NC; idx += 256) {
        const int n = idx / NC;
        const int c = idx - n * NC;
        float a = B2[c];
        const float* hn = &h_s[n * HD];
        #pragma unroll 8
        for (int k = 0; k < HD; k++)
            a = fmaf(hn[k], W2[k * NC + c], a);
        l_s[idx] = a;
    }
    __syncthreads();

    if (t < NPB) {
        const int n = t;
        float m = -1e30f;
        #pragma unroll
        for (int c = 0; c < NC; c++) m = fmaxf(m, l_s[n * NC + c]);
        float ssum = 0.0f;
        #pragma unroll
        for (int c = 0; c < NC; c++) ssum += __expf(l_s[n * NC + c] - m);
        const float lse = m + __logf(ssum);
        float* o = out + (size_t)(node0 + n) * NC;
        #pragma unroll
        for (int c = 0; c < NC; c++) o[c] = l_s[n * NC + c] - lse;
    }
}

extern "C" void kernel_launch(void* const* d_in, const int* in_sizes, int n_in,
                              void* d_out, int out_size, void* d_ws, size_t ws_size,
                              hipStream_t stream) {
    const float* feats = (const float*)d_in[0];
    const int* src = (const int*)d_in[1];
    const int* dst = (const int*)d_in[2];
    const float* W1 = (const float*)d_in[3];
    const float* B1 = (const float*)d_in[4];
    const float* W2 = (const float*)d_in[5];
    const float* B2 = (const float*)d_in[6];
    float* out = (float*)d_out;

    auto rnd = [](size_t b) { return (b + 255) & ~(size_t)255; };
    const size_t degB = rnd((size_t)NN * 4);

    // pick y storage dtype + chunk width so everything fits in ws
    int ybf = 0, logC = -1;
    size_t yB = rnd((size_t)NN * IND * 4);
    for (int pass = 0; pass < 2 && logC < 0; pass++) {
        if (pass == 1) { ybf = 1; yB = rnd((size_t)NN * IND * 2); }
        for (int lc = 7; lc >= 2; lc--) {
            size_t chunk = rnd(((size_t)NN << lc) * 4);
            if (degB + yB + 3 * chunk <= ws_size) { logC = lc; break; }
        }
    }
    if (logC < 0) logC = 2; // last resort: assume it fits

    char* base = (char*)d_ws;
    size_t off = 0;
    float* deg = (float*)(base + off); off += degB;
    void*  ybuf = (void*)(base + off); off += yB;
    const size_t chunkB = rnd(((size_t)NN << logC) * 4);
    float* xc = (float*)(base + off); off += chunkB;
    float* xn = (float*)(base + off); off += chunkB;
    float* yc = (float*)(base + off);

    hipMemsetAsync(deg, 0, (size_t)NN * 4, stream);
    deg_k<<<(NE + 255) / 256, 256, 0, stream>>>(dst, deg, NE);
    norm_k<<<(NN + 255) / 256, 256, 0, stream>>>(deg, NN);

    const int C = 1 << logC;
    const int total = NN * C;
    const int n4 = total / 4;
    const int nchunks = IND / C;
    for (int ch = 0; ch < nchunks; ch++) {
        const int col0 = ch * C;
        gather_init_k<<<(total + 255) / 256, 256, 0, stream>>>(feats, xc, yc,
                                                               col0, logC, total);
        for (int k = 0; k < 3; k++) {
            hipMemsetAsync(xn, 0, (size_t)total * 4, stream);
            const long long sthreads = (long long)NE << (logC - 2);
            scatter_k<<<(int)((sthreads + 255) / 256), 256, 0, stream>>>(
                xc, xn, src, dst, deg, NE, logC - 2);
            accum_k<<<(n4 + 255) / 256, 256, 0, stream>>>((float4*)yc, (const float4*)xn, n4);
            float* tmp = xc; xc = xn; xn = tmp;
        }
        if (ybf) store_y_k<1><<<(total + 255) / 256, 256, 0, stream>>>(yc, ybuf, col0, logC, total);
        else     store_y_k<0><<<(total + 255) / 256, 256, 0, stream>>>(yc, ybuf, col0, logC, total);
    }

    if (ybf) mlp_k<1><<<NN / NPB, 256, 0, stream>>>(ybuf, W1, B1, W2, B2, out);
    else     mlp_k<0><<<NN / NPB, 256, 0, stream>>>(ybuf, W1, B1, W2, B2, out);
}

// Round 4
// 1012.958 us; speedup vs baseline: 3.9166x; 3.9166x over previous
//
#include <hip/hip_runtime.h>

#define NN 100000
#define NE 640000
#define IND 128
#define HD 256
#define NC 40
#define NPB 32

__global__ void deg_i_k(const int* __restrict__ dst, int* __restrict__ deg, int E) {
    int g = blockIdx.x * 256 + threadIdx.x;
    if (g < E) atomicAdd(&deg[dst[g]], 1);
}

__global__ void norm_k(const int* __restrict__ deg, float* __restrict__ norm, int N) {
    int g = blockIdx.x * 256 + threadIdx.x;
    if (g < N) norm[g] = rsqrtf(fmaxf((float)deg[g], 1.0f));
}

// single-block exclusive prefix sum: rowptr[0..N], 1024 threads, chunked
__global__ __launch_bounds__(1024) void scan_k(const int* __restrict__ deg,
                                               int* __restrict__ rowptr, int N) {
    __shared__ int sums[1024];
    const int t = threadIdx.x;
    const int chunk = (N + 1023) / 1024;
    const int beg = t * chunk;
    const int end = min(beg + chunk, N);
    int s = 0;
    for (int i = beg; i < end; i++) s += deg[i];
    sums[t] = s;
    __syncthreads();
    for (int off = 1; off < 1024; off <<= 1) {
        int v = (t >= off) ? sums[t - off] : 0;
        __syncthreads();
        sums[t] += v;
        __syncthreads();
    }
    int run = (t == 0) ? 0 : sums[t - 1];
    for (int i = beg; i < end; i++) { rowptr[i] = run; run += deg[i]; }
    if (t == 0) rowptr[N] = sums[1023];
}

// bucket-fill CSR: col = src index, val = norm[src]*norm[dst]
__global__ void fill_k(const int* __restrict__ src, const int* __restrict__ dst,
                       const float* __restrict__ norm, int* __restrict__ cursor,
                       int* __restrict__ col, float* __restrict__ val, int E) {
    int e = blockIdx.x * 256 + threadIdx.x;
    if (e >= E) return;
    int s = src[e], d = dst[e];
    int pos = atomicAdd(&cursor[d], 1);
    col[pos] = s;
    val[pos] = norm[s] * norm[d];
}

// gather-SpMM: one wave per dst row. xn[d] = sum_e w_e * x[col_e];
// FIRST: yc[d] = x[d] + xn[d]  (x==feats on the first step), else yc[d] += xn[d].
template <int FIRST>
__global__ __launch_bounds__(256) void spmm_k(
    const float* __restrict__ x, float* __restrict__ xn, float* __restrict__ yc,
    const int* __restrict__ rowptr, const int* __restrict__ col,
    const float* __restrict__ val, int N)
{
    const int wid = (blockIdx.x * 256 + threadIdx.x) >> 6;
    const int lane = threadIdx.x & 63;
    if (wid >= N) return;
    const int d = wid;
    const int beg = rowptr[d], end = rowptr[d + 1];
    float a0 = 0.0f, a1 = 0.0f;
    for (int e = beg; e < end; e++) {
        const int s = col[e];
        const float w = val[e];
        const float2 v = *((const float2*)(x + (size_t)s * IND) + lane);
        a0 = fmaf(v.x, w, a0);
        a1 = fmaf(v.y, w, a1);
    }
    *((float2*)(xn + (size_t)d * IND) + lane) = make_float2(a0, a1);
    float2* ycp = (float2*)(yc + (size_t)d * IND) + lane;
    if (FIRST) {
        const float2 f = *((const float2*)(x + (size_t)d * IND) + lane);
        *ycp = make_float2(f.x + a0, f.y + a1);
    } else {
        const float2 o = *ycp;
        *ycp = make_float2(o.x + a0, o.y + a1);
    }
}

// Fused MLP + log_softmax. 32 nodes/block, thread t owns hidden unit t.
__global__ __launch_bounds__(256) void mlp_k(
    const float* __restrict__ y, const float* __restrict__ W1,
    const float* __restrict__ B1, const float* __restrict__ W2,
    const float* __restrict__ B2, float* __restrict__ out) {
    __shared__ float y_s[NPB * IND];   // 16 KB
    __shared__ float h_s[NPB * HD];    // 32 KB
    __shared__ float l_s[NPB * NC];    // 5 KB
    const int t = threadIdx.x;
    const int node0 = blockIdx.x * NPB;

    for (int idx = t; idx < NPB * IND; idx += 256)
        y_s[idx] = y[(size_t)node0 * IND + idx] * 0.25f;  // 1/(K+1)
    __syncthreads();

    float acc[NPB];
    {
        const float bb = B1[t];
        #pragma unroll
        for (int n = 0; n < NPB; n++) acc[n] = bb;
    }
    for (int i = 0; i < IND; i += 4) {
        const float w0 = W1[(i + 0) * HD + t];
        const float w1 = W1[(i + 1) * HD + t];
        const float w2 = W1[(i + 2) * HD + t];
        const float w3 = W1[(i + 3) * HD + t];
        #pragma unroll
        for (int n = 0; n < NPB; n++) {
            const float4 v = *(const float4*)&y_s[n * IND + i];
            float a = acc[n];
            a = fmaf(v.x, w0, a);
            a = fmaf(v.y, w1, a);
            a = fmaf(v.z, w2, a);
            a = fmaf(v.w, w3, a);
            acc[n] = a;
        }
    }
    #pragma unroll
    for (int n = 0; n < NPB; n++) h_s[n * HD + t] = fmaxf(acc[n], 0.0f);
    __syncthreads();

    for (int idx = t; idx < NPB * NC; idx += 256) {
        const int n = idx / NC;
        const int c = idx - n * NC;
        float a = B2[c];
        const float* hn = &h_s[n * HD];
        #pragma unroll 8
        for (int k = 0; k < HD; k++)
            a = fmaf(hn[k], W2[k * NC + c], a);
        l_s[idx] = a;
    }
    __syncthreads();

    if (t < NPB) {
        const int n = t;
        float m = -1e30f;
        #pragma unroll
        for (int c = 0; c < NC; c++) m = fmaxf(m, l_s[n * NC + c]);
        float ssum = 0.0f;
        #pragma unroll
        for (int c = 0; c < NC; c++) ssum += __expf(l_s[n * NC + c] - m);
        const float lse = m + __logf(ssum);
        float* o = out + (size_t)(node0 + n) * NC;
        #pragma unroll
        for (int c = 0; c < NC; c++) o[c] = l_s[n * NC + c] - lse;
    }
}

extern "C" void kernel_launch(void* const* d_in, const int* in_sizes, int n_in,
                              void* d_out, int out_size, void* d_ws, size_t ws_size,
                              hipStream_t stream) {
    const float* feats = (const float*)d_in[0];
    const int* src = (const int*)d_in[1];
    const int* dst = (const int*)d_in[2];
    const float* W1 = (const float*)d_in[3];
    const float* B1 = (const float*)d_in[4];
    const float* W2 = (const float*)d_in[5];
    const float* B2 = (const float*)d_in[6];
    float* out = (float*)d_out;

    char* base = (char*)d_ws;
    size_t off = 0;
    auto alloc = [&](size_t bytes) -> void* {
        void* p = base + off;
        off += (bytes + 255) & ~(size_t)255;
        return p;
    };
    int*   deg    = (int*)  alloc((size_t)NN * 4);
    float* norm   = (float*)alloc((size_t)NN * 4);
    int*   rowptr = (int*)  alloc((size_t)(NN + 1) * 4);
    int*   cursor = (int*)  alloc((size_t)NN * 4);
    int*   col    = (int*)  alloc((size_t)NE * 4);
    float* val    = (float*)alloc((size_t)NE * 4);
    float* xA     = (float*)alloc((size_t)NN * IND * 4);
    float* xB     = (float*)alloc((size_t)NN * IND * 4);
    float* yc     = (float*)alloc((size_t)NN * IND * 4);

    hipMemsetAsync(deg, 0, (size_t)NN * 4, stream);
    deg_i_k<<<(NE + 255) / 256, 256, 0, stream>>>(dst, deg, NE);
    norm_k<<<(NN + 255) / 256, 256, 0, stream>>>(deg, norm, NN);
    scan_k<<<1, 1024, 0, stream>>>(deg, rowptr, NN);
    hipMemcpyAsync(cursor, rowptr, (size_t)NN * 4, hipMemcpyDeviceToDevice, stream);
    fill_k<<<(NE + 255) / 256, 256, 0, stream>>>(src, dst, norm, cursor, col, val, NE);

    const int sgrid = (NN * 64 + 255) / 256;
    spmm_k<1><<<sgrid, 256, 0, stream>>>(feats, xA, yc, rowptr, col, val, NN);
    spmm_k<0><<<sgrid, 256, 0, stream>>>(xA, xB, yc, rowptr, col, val, NN);
    spmm_k<0><<<sgrid, 256, 0, stream>>>(xB, xA, yc, rowptr, col, val, NN);

    mlp_k<<<NN / NPB, 256, 0, stream>>>(yc, W1, B1, W2, B2, out);
}

// Round 5
// 624.185 us; speedup vs baseline: 6.3560x; 1.6228x over previous
//
#include <hip/hip_runtime.h>

#define NN 100000
#define NE 640000
#define IND 128
#define HD 256
#define NC 40
#define MT 64      // nodes per block in MLP
#define HPAD 264   // h_s row stride (bf16 elems), padded vs 256 to break bank stride
#define LPAD 52    // l_s row stride (f32), padded vs 48

typedef unsigned short u16;
typedef __attribute__((ext_vector_type(8))) short bf16x8;
typedef __attribute__((ext_vector_type(4))) float f32x4;

__device__ __forceinline__ float bf2f(u16 u) {
    union { unsigned int i; float f; } c; c.i = ((unsigned int)u) << 16; return c.f;
}
__device__ __forceinline__ u16 f2bf(float f) {
    union { float f; unsigned int i; } c; c.f = f;
    unsigned int i = c.i;
    return (u16)((i + 0x7FFFu + ((i >> 16) & 1u)) >> 16); // RNE
}

__global__ void deg_i_k(const int* __restrict__ dst, int* __restrict__ deg, int E) {
    int g = blockIdx.x * 256 + threadIdx.x;
    if (g < E) atomicAdd(&deg[dst[g]], 1);
}

__global__ void norm_k(const int* __restrict__ deg, float* __restrict__ norm, int N) {
    int g = blockIdx.x * 256 + threadIdx.x;
    if (g < N) norm[g] = rsqrtf(fmaxf((float)deg[g], 1.0f));
}

// single-block exclusive prefix sum: rowptr[0..N]
__global__ __launch_bounds__(1024) void scan_k(const int* __restrict__ deg,
                                               int* __restrict__ rowptr, int N) {
    __shared__ int sums[1024];
    const int t = threadIdx.x;
    const int chunk = (N + 1023) / 1024;
    const int beg = t * chunk;
    const int end = min(beg + chunk, N);
    int s = 0;
    for (int i = beg; i < end; i++) s += deg[i];
    sums[t] = s;
    __syncthreads();
    for (int off = 1; off < 1024; off <<= 1) {
        int v = (t >= off) ? sums[t - off] : 0;
        __syncthreads();
        sums[t] += v;
        __syncthreads();
    }
    int run = (t == 0) ? 0 : sums[t - 1];
    for (int i = beg; i < end; i++) { rowptr[i] = run; run += deg[i]; }
    if (t == 0) rowptr[N] = sums[1023];
}

__global__ void fill_k(const int* __restrict__ src, const int* __restrict__ dst,
                       const float* __restrict__ norm, int* __restrict__ cursor,
                       int* __restrict__ col, float* __restrict__ val, int E) {
    int e = blockIdx.x * 256 + threadIdx.x;
    if (e >= E) return;
    int s = src[e], d = dst[e];
    int pos = atomicAdd(&cursor[d], 1);
    col[pos] = s;
    val[pos] = norm[s] * norm[d];
}

// gather-SpMM: one wave per dst row; fuses y accumulation.
template <int FIRST>
__global__ __launch_bounds__(256) void spmm_k(
    const float* __restrict__ x, float* __restrict__ xn, float* __restrict__ yc,
    const int* __restrict__ rowptr, const int* __restrict__ col,
    const float* __restrict__ val, int N)
{
    const int wid = (blockIdx.x * 256 + threadIdx.x) >> 6;
    const int lane = threadIdx.x & 63;
    if (wid >= N) return;
    const int d = wid;
    const int beg = rowptr[d], end = rowptr[d + 1];
    float a0 = 0.0f, a1 = 0.0f;
    for (int e = beg; e < end; e++) {
        const int s = col[e];
        const float w = val[e];
        const float2 v = *((const float2*)(x + (size_t)s * IND) + lane);
        a0 = fmaf(v.x, w, a0);
        a1 = fmaf(v.y, w, a1);
    }
    *((float2*)(xn + (size_t)d * IND) + lane) = make_float2(a0, a1);
    float2* ycp = (float2*)(yc + (size_t)d * IND) + lane;
    if (FIRST) {
        const float2 f = *((const float2*)(x + (size_t)d * IND) + lane);
        *ycp = make_float2(f.x + a0, f.y + a1);
    } else {
        const float2 o = *ycp;
        *ycp = make_float2(o.x + a0, o.y + a1);
    }
}

// Pack W1 [128x256] fp32 -> bf16 fragment-major: [ct(16)][ks(4)][lane(64)][j(8)]
__global__ void pack_w1_k(const float* __restrict__ W1, u16* __restrict__ pw1) {
    int idx = blockIdx.x * 256 + threadIdx.x;
    if (idx >= 16 * 4 * 64) return;
    int lane = idx & 63, fid = idx >> 6;
    int ks = fid & 3, ct = fid >> 2;
    int quad = lane >> 4, m = lane & 15;
    int n = ct * 16 + m;
    u16* o = pw1 + (size_t)idx * 8;
    #pragma unroll
    for (int j = 0; j < 8; j++) {
        int k = ks * 32 + quad * 8 + j;
        o[j] = f2bf(W1[k * HD + n]);
    }
}

// Pack W2 [256x40] fp32 -> bf16 fragment-major padded to 48 cols: [ct(3)][ks(8)][lane(64)][j(8)]
__global__ void pack_w2_k(const float* __restrict__ W2, u16* __restrict__ pw2) {
    int idx = blockIdx.x * 256 + threadIdx.x;
    if (idx >= 3 * 8 * 64) return;
    int lane = idx & 63, fid = idx >> 6;
    int ks = fid & 7, ct = fid >> 3;
    int quad = lane >> 4, m = lane & 15;
    int n = ct * 16 + m;
    u16* o = pw2 + (size_t)idx * 8;
    #pragma unroll
    for (int j = 0; j < 8; j++) {
        int k = ks * 32 + quad * 8 + j;
        o[j] = (n < NC) ? f2bf(W2[k * NC + n]) : (u16)0;
    }
}

// MFMA MLP: 64 nodes/block, 4 waves x 16-node tiles.
// L1: H[64x256] = relu((Y/4)[64x128] @ W1 + b1), split-bf16 A (2 MFMAs/tile).
// L2: logits[64x48] = H @ W2pad + b2, then log_softmax -> out.
__global__ __launch_bounds__(256) void mlp_mfma_k(
    const float* __restrict__ y, const u16* __restrict__ pw1,
    const float* __restrict__ B1, const u16* __restrict__ pw2,
    const float* __restrict__ B2, float* __restrict__ out, int N)
{
    __shared__ u16 h_s[MT * HPAD];     // 33 KB
    __shared__ float l_s[MT * LPAD];   // 13.3 KB
    const int t = threadIdx.x;
    const int w = t >> 6, lane = t & 63;
    const int quad = lane >> 4, m = lane & 15;
    const int node0 = blockIdx.x * MT;

    // ---- load A fragments (Y), split hi/lo, scale by 1/(K+1)=0.25 ----
    int nodeA = node0 + w * 16 + m;
    if (nodeA > N - 1) nodeA = N - 1;
    bf16x8 ah[4], al[4];
    #pragma unroll
    for (int ks = 0; ks < 4; ks++) {
        const float* yp = y + (size_t)nodeA * IND + ks * 32 + quad * 8;
        const float4 v0 = *(const float4*)yp;
        const float4 v1 = *(const float4*)(yp + 4);
        float vv[8] = { v0.x, v0.y, v0.z, v0.w, v1.x, v1.y, v1.z, v1.w };
        #pragma unroll
        for (int j = 0; j < 8; j++) {
            float v = vv[j] * 0.25f;
            u16 h = f2bf(v);
            u16 l = f2bf(v - bf2f(h));
            ah[ks][j] = (short)h;
            al[ks][j] = (short)l;
        }
    }

    // ---- layer 1: 16 column tiles ----
    #pragma unroll 4
    for (int ct = 0; ct < 16; ct++) {
        f32x4 acc = { 0.f, 0.f, 0.f, 0.f };
        #pragma unroll
        for (int ks = 0; ks < 4; ks++) {
            const bf16x8 b = *(const bf16x8*)(pw1 + (size_t)((ct * 4 + ks) * 64 + lane) * 8);
            acc = __builtin_amdgcn_mfma_f32_16x16x32_bf16(al[ks], b, acc, 0, 0, 0);
            acc = __builtin_amdgcn_mfma_f32_16x16x32_bf16(ah[ks], b, acc, 0, 0, 0);
        }
        const float b1c = B1[ct * 16 + m];
        #pragma unroll
        for (int r = 0; r < 4; r++) {
            const float hv = fmaxf(acc[r] + b1c, 0.0f);
            h_s[(w * 16 + quad * 4 + r) * HPAD + ct * 16 + m] = f2bf(hv);
        }
    }
    // no barrier needed: each wave reads only its own h_s rows (lgkmcnt orders within wave)

    // ---- layer 2: 3 column tiles over K=256 ----
    f32x4 acc2[3];
    #pragma unroll
    for (int ct = 0; ct < 3; ct++) acc2[ct] = (f32x4){ 0.f, 0.f, 0.f, 0.f };
    #pragma unroll
    for (int ks = 0; ks < 8; ks++) {
        const bf16x8 a = *(const bf16x8*)&h_s[(w * 16 + m) * HPAD + ks * 32 + quad * 8];
        #pragma unroll
        for (int ct = 0; ct < 3; ct++) {
            const bf16x8 b = *(const bf16x8*)(pw2 + (size_t)((ct * 8 + ks) * 64 + lane) * 8);
            acc2[ct] = __builtin_amdgcn_mfma_f32_16x16x32_bf16(a, b, acc2[ct], 0, 0, 0);
        }
    }
    #pragma unroll
    for (int ct = 0; ct < 3; ct++) {
        const int cg = ct * 16 + m;
        const float b2c = (cg < NC) ? B2[cg] : 0.0f;
        #pragma unroll
        for (int r = 0; r < 4; r++)
            l_s[(w * 16 + quad * 4 + r) * LPAD + cg] = acc2[ct][r] + b2c;
    }
    __syncthreads();

    // ---- log_softmax epilogue: thread t<64 handles node t ----
    if (t < MT) {
        const int node = node0 + t;
        if (node < N) {
            const float* ln = &l_s[t * LPAD];
            float mx = -1e30f;
            #pragma unroll
            for (int c = 0; c < NC; c++) mx = fmaxf(mx, ln[c]);
            float s = 0.0f;
            #pragma unroll
            for (int c = 0; c < NC; c++) s += __expf(ln[c] - mx);
            const float lse = mx + __logf(s);
            float4* o = (float4*)(out + (size_t)node * NC);
            #pragma unroll
            for (int c4 = 0; c4 < NC / 4; c4++) {
                float4 v;
                v.x = ln[c4 * 4 + 0] - lse;
                v.y = ln[c4 * 4 + 1] - lse;
                v.z = ln[c4 * 4 + 2] - lse;
                v.w = ln[c4 * 4 + 3] - lse;
                o[c4] = v;
            }
        }
    }
}

extern "C" void kernel_launch(void* const* d_in, const int* in_sizes, int n_in,
                              void* d_out, int out_size, void* d_ws, size_t ws_size,
                              hipStream_t stream) {
    const float* feats = (const float*)d_in[0];
    const int* src = (const int*)d_in[1];
    const int* dst = (const int*)d_in[2];
    const float* W1 = (const float*)d_in[3];
    const float* B1 = (const float*)d_in[4];
    const float* W2 = (const float*)d_in[5];
    const float* B2 = (const float*)d_in[6];
    float* out = (float*)d_out;

    char* base = (char*)d_ws;
    size_t off = 0;
    auto alloc = [&](size_t bytes) -> void* {
        void* p = base + off;
        off += (bytes + 255) & ~(size_t)255;
        return p;
    };
    int*   deg    = (int*)  alloc((size_t)NN * 4);
    float* norm   = (float*)alloc((size_t)NN * 4);
    int*   rowptr = (int*)  alloc((size_t)(NN + 1) * 4);
    int*   cursor = (int*)  alloc((size_t)NN * 4);
    int*   col    = (int*)  alloc((size_t)NE * 4);
    float* val    = (float*)alloc((size_t)NE * 4);
    u16*   pw1    = (u16*)  alloc((size_t)16 * 4 * 64 * 8 * 2);
    u16*   pw2    = (u16*)  alloc((size_t)3 * 8 * 64 * 8 * 2);
    float* xA     = (float*)alloc((size_t)NN * IND * 4);
    float* xB     = (float*)alloc((size_t)NN * IND * 4);
    float* yc     = (float*)alloc((size_t)NN * IND * 4);

    hipMemsetAsync(deg, 0, (size_t)NN * 4, stream);
    deg_i_k<<<(NE + 255) / 256, 256, 0, stream>>>(dst, deg, NE);
    norm_k<<<(NN + 255) / 256, 256, 0, stream>>>(deg, norm, NN);
    scan_k<<<1, 1024, 0, stream>>>(deg, rowptr, NN);
    hipMemcpyAsync(cursor, rowptr, (size_t)NN * 4, hipMemcpyDeviceToDevice, stream);
    fill_k<<<(NE + 255) / 256, 256, 0, stream>>>(src, dst, norm, cursor, col, val, NE);
    pack_w1_k<<<(16 * 4 * 64 + 255) / 256, 256, 0, stream>>>(W1, pw1);
    pack_w2_k<<<(3 * 8 * 64 + 255) / 256, 256, 0, stream>>>(W2, pw2);

    const int sgrid = (NN * 64 + 255) / 256;
    spmm_k<1><<<sgrid, 256, 0, stream>>>(feats, xA, yc, rowptr, col, val, NN);
    spmm_k<0><<<sgrid, 256, 0, stream>>>(xA, xB, yc, rowptr, col, val, NN);
    spmm_k<0><<<sgrid, 256, 0, stream>>>(xB, xA, yc, rowptr, col, val, NN);

    const int mgrid = (NN + MT - 1) / MT;
    mlp_mfma_k<<<mgrid, 256, 0, stream>>>(yc, pw1, B1, pw2, B2, out, NN);
}

// Round 6
// 456.341 us; speedup vs baseline: 8.6938x; 1.3678x over previous
//
#include <hip/hip_runtime.h>

#define NN 100000
#define NE 640000
#define IND 128
#define HD 256
#define NC 40
#define MT 64      // nodes per block in MLP
#define HPAD 264   // h_s row stride (bf16 elems)
#define LPAD 52    // l_s row stride (f32)
#define SCH 1024   // elements per scan block
#define SNB ((NN + SCH - 1) / SCH)   // 98 scan blocks

typedef unsigned short u16;
typedef unsigned int u32;
typedef __attribute__((ext_vector_type(8))) short bf16x8;
typedef __attribute__((ext_vector_type(4))) float f32x4;

__device__ __forceinline__ float bf2f(u16 u) {
    union { u32 i; float f; } c; c.i = ((u32)u) << 16; return c.f;
}
__device__ __forceinline__ u16 f2bf(float f) {
    union { float f; u32 i; } c; c.f = f;
    u32 i = c.i;
    return (u16)((i + 0x7FFFu + ((i >> 16) & 1u)) >> 16); // RNE
}

__global__ void deg_i_k(const int* __restrict__ dst, int* __restrict__ deg, int E) {
    int g = blockIdx.x * 256 + threadIdx.x;
    if (g < E) atomicAdd(&deg[dst[g]], 1);
}

__global__ void norm_k(const int* __restrict__ deg, float* __restrict__ norm, int N) {
    int g = blockIdx.x * 256 + threadIdx.x;
    if (g < N) norm[g] = rsqrtf(fmaxf((float)deg[g], 1.0f));
}

// ---- hierarchical scan: pass1 per-block sums ----
__global__ __launch_bounds__(256) void scan1_k(const int* __restrict__ deg,
                                               int* __restrict__ bsum, int N) {
    __shared__ int s[256];
    const int t = threadIdx.x, b = blockIdx.x;
    const int base = b * SCH + t * 4;
    int acc = 0;
    #pragma unroll
    for (int j = 0; j < 4; j++) {
        int idx = base + j;
        if (idx < N) acc += deg[idx];
    }
    s[t] = acc;
    __syncthreads();
    for (int off = 128; off > 0; off >>= 1) {
        if (t < off) s[t] += s[t + off];
        __syncthreads();
    }
    if (t == 0) bsum[b] = s[0];
}

// ---- pass2: single block scans SNB block sums -> exclusive boff; writes rowptr[N] ----
__global__ __launch_bounds__(128) void scan2_k(const int* __restrict__ bsum,
                                               int* __restrict__ boff,
                                               int* __restrict__ rowptr, int N) {
    __shared__ int s[128];
    const int t = threadIdx.x;
    const int own = (t < SNB) ? bsum[t] : 0;
    s[t] = own;
    __syncthreads();
    #pragma unroll
    for (int off = 1; off < 128; off <<= 1) {
        int v = (t >= off) ? s[t - off] : 0;
        __syncthreads();
        s[t] += v;
        __syncthreads();
    }
    if (t < SNB) boff[t] = s[t] - own;
    if (t == 127) rowptr[N] = s[127];
}

// ---- pass3: block-local exclusive scan + block offset -> rowptr & cursor ----
__global__ __launch_bounds__(256) void scan3_k(const int* __restrict__ deg,
                                               const int* __restrict__ boff,
                                               int* __restrict__ rowptr,
                                               int* __restrict__ cursor, int N) {
    __shared__ int s[256];
    const int t = threadIdx.x, b = blockIdx.x;
    const int base = b * SCH + t * 4;
    int d4[4]; int own = 0;
    #pragma unroll
    for (int j = 0; j < 4; j++) {
        int idx = base + j;
        d4[j] = (idx < N) ? deg[idx] : 0;
        own += d4[j];
    }
    s[t] = own;
    __syncthreads();
    #pragma unroll
    for (int off = 1; off < 256; off <<= 1) {
        int v = (t >= off) ? s[t - off] : 0;
        __syncthreads();
        s[t] += v;
        __syncthreads();
    }
    int run = boff[b] + s[t] - own;
    #pragma unroll
    for (int j = 0; j < 4; j++) {
        int idx = base + j;
        if (idx < N) { rowptr[idx] = run; cursor[idx] = run; run += d4[j]; }
    }
}

__global__ void fill_k(const int* __restrict__ src, const int* __restrict__ dst,
                       const float* __restrict__ norm, int* __restrict__ cursor,
                       int* __restrict__ col, float* __restrict__ val, int E) {
    int e = blockIdx.x * 256 + threadIdx.x;
    if (e >= E) return;
    int s = src[e], d = dst[e];
    int pos = atomicAdd(&cursor[d], 1);
    col[pos] = s;
    val[pos] = norm[s] * norm[d];
}

// gather-SpMM, one wave per dst row, 2 feats/lane.
// FIRST: x is fp32 (feats), yc initialized = feats + xn; else x is bf16, yc += xn.
// LAST: skip xn store.
template <int FIRST, int LAST>
__global__ __launch_bounds__(256) void spmm_k(
    const void* __restrict__ x, u32* __restrict__ xn, float* __restrict__ yc,
    const int* __restrict__ rowptr, const int* __restrict__ col,
    const float* __restrict__ val, int N)
{
    const int wid = (blockIdx.x * 256 + threadIdx.x) >> 6;
    const int lane = threadIdx.x & 63;
    if (wid >= N) return;
    const int d = wid;
    const int beg = rowptr[d], end = rowptr[d + 1];
    float a0 = 0.0f, a1 = 0.0f;
    for (int e = beg; e < end; e++) {
        const int s = col[e];
        const float w = val[e];
        if (FIRST) {
            const float2 v = *((const float2*)((const float*)x + (size_t)s * IND) + lane);
            a0 = fmaf(v.x, w, a0);
            a1 = fmaf(v.y, w, a1);
        } else {
            const u32 u = ((const u32*)x)[(size_t)s * (IND / 2) + lane];
            a0 = fmaf(bf2f((u16)(u & 0xFFFFu)), w, a0);
            a1 = fmaf(bf2f((u16)(u >> 16)), w, a1);
        }
    }
    if (!LAST)
        xn[(size_t)d * (IND / 2) + lane] = (u32)f2bf(a0) | ((u32)f2bf(a1) << 16);
    float2* ycp = (float2*)(yc + (size_t)d * IND) + lane;
    if (FIRST) {
        const float2 f = *((const float2*)((const float*)x + (size_t)d * IND) + lane);
        *ycp = make_float2(f.x + a0, f.y + a1);
    } else {
        const float2 o = *ycp;
        *ycp = make_float2(o.x + a0, o.y + a1);
    }
}

// Pack W1 [128x256] fp32 -> bf16 fragment-major: [ct(16)][ks(4)][lane(64)][j(8)]
__global__ void pack_w1_k(const float* __restrict__ W1, u16* __restrict__ pw1) {
    int idx = blockIdx.x * 256 + threadIdx.x;
    if (idx >= 16 * 4 * 64) return;
    int lane = idx & 63, fid = idx >> 6;
    int ks = fid & 3, ct = fid >> 2;
    int quad = lane >> 4, m = lane & 15;
    int n = ct * 16 + m;
    u16* o = pw1 + (size_t)idx * 8;
    #pragma unroll
    for (int j = 0; j < 8; j++) {
        int k = ks * 32 + quad * 8 + j;
        o[j] = f2bf(W1[k * HD + n]);
    }
}

// Pack W2 [256x40] fp32 -> bf16 fragment-major padded to 48 cols: [ct(3)][ks(8)][lane(64)][j(8)]
__global__ void pack_w2_k(const float* __restrict__ W2, u16* __restrict__ pw2) {
    int idx = blockIdx.x * 256 + threadIdx.x;
    if (idx >= 3 * 8 * 64) return;
    int lane = idx & 63, fid = idx >> 6;
    int ks = fid & 7, ct = fid >> 3;
    int quad = lane >> 4, m = lane & 15;
    int n = ct * 16 + m;
    u16* o = pw2 + (size_t)idx * 8;
    #pragma unroll
    for (int j = 0; j < 8; j++) {
        int k = ks * 32 + quad * 8 + j;
        o[j] = (n < NC) ? f2bf(W2[k * NC + n]) : (u16)0;
    }
}

// MFMA MLP: 64 nodes/block, 4 waves x 16-node tiles, split-bf16 A for layer 1.
__global__ __launch_bounds__(256) void mlp_mfma_k(
    const float* __restrict__ y, const u16* __restrict__ pw1,
    const float* __restrict__ B1, const u16* __restrict__ pw2,
    const float* __restrict__ B2, float* __restrict__ out, int N)
{
    __shared__ u16 h_s[MT * HPAD];
    __shared__ float l_s[MT * LPAD];
    const int t = threadIdx.x;
    const int w = t >> 6, lane = t & 63;
    const int quad = lane >> 4, m = lane & 15;
    const int node0 = blockIdx.x * MT;

    int nodeA = node0 + w * 16 + m;
    if (nodeA > N - 1) nodeA = N - 1;
    bf16x8 ah[4], al[4];
    #pragma unroll
    for (int ks = 0; ks < 4; ks++) {
        const float* yp = y + (size_t)nodeA * IND + ks * 32 + quad * 8;
        const float4 v0 = *(const float4*)yp;
        const float4 v1 = *(const float4*)(yp + 4);
        float vv[8] = { v0.x, v0.y, v0.z, v0.w, v1.x, v1.y, v1.z, v1.w };
        #pragma unroll
        for (int j = 0; j < 8; j++) {
            float v = vv[j] * 0.25f;
            u16 h = f2bf(v);
            u16 l = f2bf(v - bf2f(h));
            ah[ks][j] = (short)h;
            al[ks][j] = (short)l;
        }
    }

    #pragma unroll 4
    for (int ct = 0; ct < 16; ct++) {
        f32x4 acc = { 0.f, 0.f, 0.f, 0.f };
        #pragma unroll
        for (int ks = 0; ks < 4; ks++) {
            const bf16x8 b = *(const bf16x8*)(pw1 + (size_t)((ct * 4 + ks) * 64 + lane) * 8);
            acc = __builtin_amdgcn_mfma_f32_16x16x32_bf16(al[ks], b, acc, 0, 0, 0);
            acc = __builtin_amdgcn_mfma_f32_16x16x32_bf16(ah[ks], b, acc, 0, 0, 0);
        }
        const float b1c = B1[ct * 16 + m];
        #pragma unroll
        for (int r = 0; r < 4; r++) {
            const float hv = fmaxf(acc[r] + b1c, 0.0f);
            h_s[(w * 16 + quad * 4 + r) * HPAD + ct * 16 + m] = f2bf(hv);
        }
    }

    f32x4 acc2[3];
    #pragma unroll
    for (int ct = 0; ct < 3; ct++) acc2[ct] = (f32x4){ 0.f, 0.f, 0.f, 0.f };
    #pragma unroll
    for (int ks = 0; ks < 8; ks++) {
        const bf16x8 a = *(const bf16x8*)&h_s[(w * 16 + m) * HPAD + ks * 32 + quad * 8];
        #pragma unroll
        for (int ct = 0; ct < 3; ct++) {
            const bf16x8 b = *(const bf16x8*)(pw2 + (size_t)((ct * 8 + ks) * 64 + lane) * 8);
            acc2[ct] = __builtin_amdgcn_mfma_f32_16x16x32_bf16(a, b, acc2[ct], 0, 0, 0);
        }
    }
    #pragma unroll
    for (int ct = 0; ct < 3; ct++) {
        const int cg = ct * 16 + m;
        const float b2c = (cg < NC) ? B2[cg] : 0.0f;
        #pragma unroll
        for (int r = 0; r < 4; r++)
            l_s[(w * 16 + quad * 4 + r) * LPAD + cg] = acc2[ct][r] + b2c;
    }
    __syncthreads();

    if (t < MT) {
        const int node = node0 + t;
        if (node < N) {
            const float* ln = &l_s[t * LPAD];
            float mx = -1e30f;
            #pragma unroll
            for (int c = 0; c < NC; c++) mx = fmaxf(mx, ln[c]);
            float s = 0.0f;
            #pragma unroll
            for (int c = 0; c < NC; c++) s += __expf(ln[c] - mx);
            const float lse = mx + __logf(s);
            float4* o = (float4*)(out + (size_t)node * NC);
            #pragma unroll
            for (int c4 = 0; c4 < NC / 4; c4++) {
                float4 v;
                v.x = ln[c4 * 4 + 0] - lse;
                v.y = ln[c4 * 4 + 1] - lse;
                v.z = ln[c4 * 4 + 2] - lse;
                v.w = ln[c4 * 4 + 3] - lse;
                o[c4] = v;
            }
        }
    }
}

extern "C" void kernel_launch(void* const* d_in, const int* in_sizes, int n_in,
                              void* d_out, int out_size, void* d_ws, size_t ws_size,
                              hipStream_t stream) {
    const float* feats = (const float*)d_in[0];
    const int* src = (const int*)d_in[1];
    const int* dst = (const int*)d_in[2];
    const float* W1 = (const float*)d_in[3];
    const float* B1 = (const float*)d_in[4];
    const float* W2 = (const float*)d_in[5];
    const float* B2 = (const float*)d_in[6];
    float* out = (float*)d_out;

    char* base = (char*)d_ws;
    size_t off = 0;
    auto alloc = [&](size_t bytes) -> void* {
        void* p = base + off;
        off += (bytes + 255) & ~(size_t)255;
        return p;
    };
    int*   deg    = (int*)  alloc((size_t)NN * 4);
    float* norm   = (float*)alloc((size_t)NN * 4);
    int*   rowptr = (int*)  alloc((size_t)(NN + 1) * 4);
    int*   cursor = (int*)  alloc((size_t)NN * 4);
    int*   bsum   = (int*)  alloc((size_t)SNB * 4);
    int*   boff   = (int*)  alloc((size_t)SNB * 4);
    int*   col    = (int*)  alloc((size_t)NE * 4);
    float* val    = (float*)alloc((size_t)NE * 4);
    u16*   pw1    = (u16*)  alloc((size_t)16 * 4 * 64 * 8 * 2);
    u16*   pw2    = (u16*)  alloc((size_t)3 * 8 * 64 * 8 * 2);
    u32*   xA     = (u32*)  alloc((size_t)NN * (IND / 2) * 4);  // bf16x2 packed
    u32*   xB     = (u32*)  alloc((size_t)NN * (IND / 2) * 4);
    float* yc     = (float*)alloc((size_t)NN * IND * 4);

    hipMemsetAsync(deg, 0, (size_t)NN * 4, stream);
    deg_i_k<<<(NE + 255) / 256, 256, 0, stream>>>(dst, deg, NE);
    norm_k<<<(NN + 255) / 256, 256, 0, stream>>>(deg, norm, NN);
    scan1_k<<<SNB, 256, 0, stream>>>(deg, bsum, NN);
    scan2_k<<<1, 128, 0, stream>>>(bsum, boff, rowptr, NN);
    scan3_k<<<SNB, 256, 0, stream>>>(deg, boff, rowptr, cursor, NN);
    fill_k<<<(NE + 255) / 256, 256, 0, stream>>>(src, dst, norm, cursor, col, val, NE);
    pack_w1_k<<<(16 * 4 * 64 + 255) / 256, 256, 0, stream>>>(W1, pw1);
    pack_w2_k<<<(3 * 8 * 64 + 255) / 256, 256, 0, stream>>>(W2, pw2);

    const int sgrid = (NN * 64 + 255) / 256;
    spmm_k<1, 0><<<sgrid, 256, 0, stream>>>(feats, xA, yc, rowptr, col, val, NN);
    spmm_k<0, 0><<<sgrid, 256, 0, stream>>>(xA, xB, yc, rowptr, col, val, NN);
    spmm_k<0, 1><<<sgrid, 256, 0, stream>>>(xB, xA, yc, rowptr, col, val, NN);

    const int mgrid = (NN + MT - 1) / MT;
    mlp_mfma_k<<<mgrid, 256, 0, stream>>>(yc, pw1, B1, pw2, B2, out, NN);
}

// Round 7
// 360.116 us; speedup vs baseline: 11.0168x; 1.2672x over previous
//
#include <hip/hip_runtime.h>

#define NN 100000
#define NE 640000
#define IND 128
#define HD 256
#define NC 40
#define MT 64      // nodes per block in MLP
#define HPAD 264   // h_s row stride (bf16 elems)
#define LPAD 52    // l_s row stride (f32)
#define SCH 1024   // elements per scan block
#define SNB ((NN + SCH - 1) / SCH)   // 98 scan blocks

typedef unsigned short u16;
typedef unsigned int u32;
typedef __attribute__((ext_vector_type(8))) short bf16x8;
typedef __attribute__((ext_vector_type(4))) float f32x4;

__device__ __forceinline__ float bf2f(u16 u) {
    union { u32 i; float f; } c; c.i = ((u32)u) << 16; return c.f;
}
__device__ __forceinline__ u16 f2bf(float f) {
    union { float f; u32 i; } c; c.f = f;
    u32 i = c.i;
    return (u16)((i + 0x7FFFu + ((i >> 16) & 1u)) >> 16); // RNE
}

__global__ void deg_i_k(const int* __restrict__ dst, int* __restrict__ deg, int E) {
    int g = blockIdx.x * 256 + threadIdx.x;
    if (g < E) atomicAdd(&deg[dst[g]], 1);
}

__global__ void norm_k(const int* __restrict__ deg, float* __restrict__ norm, int N) {
    int g = blockIdx.x * 256 + threadIdx.x;
    if (g < N) norm[g] = rsqrtf(fmaxf((float)deg[g], 1.0f));
}

// feats fp32 -> packed bf16x2
__global__ void cvt_k(const float2* __restrict__ f, u32* __restrict__ xb, int n) {
    int g = blockIdx.x * 256 + threadIdx.x;
    if (g >= n) return;
    float2 v = f[g];
    xb[g] = (u32)f2bf(v.x) | ((u32)f2bf(v.y) << 16);
}

// ---- hierarchical scan ----
__global__ __launch_bounds__(256) void scan1_k(const int* __restrict__ deg,
                                               int* __restrict__ bsum, int N) {
    __shared__ int s[256];
    const int t = threadIdx.x, b = blockIdx.x;
    const int base = b * SCH + t * 4;
    int acc = 0;
    #pragma unroll
    for (int j = 0; j < 4; j++) {
        int idx = base + j;
        if (idx < N) acc += deg[idx];
    }
    s[t] = acc;
    __syncthreads();
    for (int off = 128; off > 0; off >>= 1) {
        if (t < off) s[t] += s[t + off];
        __syncthreads();
    }
    if (t == 0) bsum[b] = s[0];
}

__global__ __launch_bounds__(128) void scan2_k(const int* __restrict__ bsum,
                                               int* __restrict__ boff,
                                               int* __restrict__ rowptr, int N) {
    __shared__ int s[128];
    const int t = threadIdx.x;
    const int own = (t < SNB) ? bsum[t] : 0;
    s[t] = own;
    __syncthreads();
    #pragma unroll
    for (int off = 1; off < 128; off <<= 1) {
        int v = (t >= off) ? s[t - off] : 0;
        __syncthreads();
        s[t] += v;
        __syncthreads();
    }
    if (t < SNB) boff[t] = s[t] - own;
    if (t == 127) rowptr[N] = s[127];
}

__global__ __launch_bounds__(256) void scan3_k(const int* __restrict__ deg,
                                               const int* __restrict__ boff,
                                               int* __restrict__ rowptr,
                                               int* __restrict__ cursor, int N) {
    __shared__ int s[256];
    const int t = threadIdx.x, b = blockIdx.x;
    const int base = b * SCH + t * 4;
    int d4[4]; int own = 0;
    #pragma unroll
    for (int j = 0; j < 4; j++) {
        int idx = base + j;
        d4[j] = (idx < N) ? deg[idx] : 0;
        own += d4[j];
    }
    s[t] = own;
    __syncthreads();
    #pragma unroll
    for (int off = 1; off < 256; off <<= 1) {
        int v = (t >= off) ? s[t - off] : 0;
        __syncthreads();
        s[t] += v;
        __syncthreads();
    }
    int run = boff[b] + s[t] - own;
    #pragma unroll
    for (int j = 0; j < 4; j++) {
        int idx = base + j;
        if (idx < N) { rowptr[idx] = run; cursor[idx] = run; run += d4[j]; }
    }
}

__global__ void fill_k(const int* __restrict__ src, const int* __restrict__ dst,
                       const float* __restrict__ norm, int* __restrict__ cursor,
                       int* __restrict__ col, float* __restrict__ val, int E) {
    int e = blockIdx.x * 256 + threadIdx.x;
    if (e >= E) return;
    int s = src[e], d = dst[e];
    int pos = atomicAdd(&cursor[d], 1);
    col[pos] = s;
    val[pos] = norm[s] * norm[d];
}

// gather-SpMM, one wave per dst row, bf16 x, 2 feats/lane.
// Edge loop in predicated batches of 4: col/val broadcast loads + 4 independent
// gathers in flight -> one wait per batch instead of per edge.
// FIRST: yc = x_row + a; else yc += a.  LAST: skip xn store.
template <int FIRST, int LAST>
__global__ __launch_bounds__(256) void spmm_k(
    const u32* __restrict__ x, u32* __restrict__ xn, float* __restrict__ yc,
    const int* __restrict__ rowptr, const int* __restrict__ col,
    const float* __restrict__ val, int N)
{
    const int wid = (blockIdx.x * 256 + threadIdx.x) >> 6;
    const int lane = threadIdx.x & 63;
    if (wid >= N) return;
    const int beg = rowptr[wid], end = rowptr[wid + 1];
    float a0 = 0.0f, a1 = 0.0f;
    for (int e = beg; e < end; e += 4) {
        int   c[4]; float wv[4]; u32 u[4];
        #pragma unroll
        for (int j = 0; j < 4; j++) {
            const int ee = e + j;
            const int es = (ee < end) ? ee : (end - 1);
            c[j] = col[es];
            wv[j] = (ee < end) ? val[es] : 0.0f;
        }
        #pragma unroll
        for (int j = 0; j < 4; j++)
            u[j] = x[(size_t)c[j] * (IND / 2) + lane];
        #pragma unroll
        for (int j = 0; j < 4; j++) {
            a0 = fmaf(bf2f((u16)(u[j] & 0xFFFFu)), wv[j], a0);
            a1 = fmaf(bf2f((u16)(u[j] >> 16)),     wv[j], a1);
        }
    }
    if (!LAST)
        xn[(size_t)wid * (IND / 2) + lane] = (u32)f2bf(a0) | ((u32)f2bf(a1) << 16);
    float2* ycp = (float2*)(yc + (size_t)wid * IND) + lane;
    if (FIRST) {
        const u32 u = x[(size_t)wid * (IND / 2) + lane];
        *ycp = make_float2(bf2f((u16)(u & 0xFFFFu)) + a0, bf2f((u16)(u >> 16)) + a1);
    } else {
        const float2 o = *ycp;
        *ycp = make_float2(o.x + a0, o.y + a1);
    }
}

// Pack W1 [128x256] fp32 -> bf16 fragment-major: [ct(16)][ks(4)][lane(64)][j(8)]
__global__ void pack_w1_k(const float* __restrict__ W1, u16* __restrict__ pw1) {
    int idx = blockIdx.x * 256 + threadIdx.x;
    if (idx >= 16 * 4 * 64) return;
    int lane = idx & 63, fid = idx >> 6;
    int ks = fid & 3, ct = fid >> 2;
    int quad = lane >> 4, m = lane & 15;
    int n = ct * 16 + m;
    u16* o = pw1 + (size_t)idx * 8;
    #pragma unroll
    for (int j = 0; j < 8; j++) {
        int k = ks * 32 + quad * 8 + j;
        o[j] = f2bf(W1[k * HD + n]);
    }
}

// Pack W2 [256x40] fp32 -> bf16 fragment-major padded to 48 cols: [ct(3)][ks(8)][lane(64)][j(8)]
__global__ void pack_w2_k(const float* __restrict__ W2, u16* __restrict__ pw2) {
    int idx = blockIdx.x * 256 + threadIdx.x;
    if (idx >= 3 * 8 * 64) return;
    int lane = idx & 63, fid = idx >> 6;
    int ks = fid & 7, ct = fid >> 3;
    int quad = lane >> 4, m = lane & 15;
    int n = ct * 16 + m;
    u16* o = pw2 + (size_t)idx * 8;
    #pragma unroll
    for (int j = 0; j < 8; j++) {
        int k = ks * 32 + quad * 8 + j;
        o[j] = (n < NC) ? f2bf(W2[k * NC + n]) : (u16)0;
    }
}

// MFMA MLP: 64 nodes/block, 4 waves x 16-node tiles, split-bf16 A for layer 1.
__global__ __launch_bounds__(256) void mlp_mfma_k(
    const float* __restrict__ y, const u16* __restrict__ pw1,
    const float* __restrict__ B1, const u16* __restrict__ pw2,
    const float* __restrict__ B2, float* __restrict__ out, int N)
{
    __shared__ u16 h_s[MT * HPAD];
    __shared__ float l_s[MT * LPAD];
    const int t = threadIdx.x;
    const int w = t >> 6, lane = t & 63;
    const int quad = lane >> 4, m = lane & 15;
    const int node0 = blockIdx.x * MT;

    int nodeA = node0 + w * 16 + m;
    if (nodeA > N - 1) nodeA = N - 1;
    bf16x8 ah[4], al[4];
    #pragma unroll
    for (int ks = 0; ks < 4; ks++) {
        const float* yp = y + (size_t)nodeA * IND + ks * 32 + quad * 8;
        const float4 v0 = *(const float4*)yp;
        const float4 v1 = *(const float4*)(yp + 4);
        float vv[8] = { v0.x, v0.y, v0.z, v0.w, v1.x, v1.y, v1.z, v1.w };
        #pragma unroll
        for (int j = 0; j < 8; j++) {
            float v = vv[j] * 0.25f;
            u16 h = f2bf(v);
            u16 l = f2bf(v - bf2f(h));
            ah[ks][j] = (short)h;
            al[ks][j] = (short)l;
        }
    }

    #pragma unroll 4
    for (int ct = 0; ct < 16; ct++) {
        f32x4 acc = { 0.f, 0.f, 0.f, 0.f };
        #pragma unroll
        for (int ks = 0; ks < 4; ks++) {
            const bf16x8 b = *(const bf16x8*)(pw1 + (size_t)((ct * 4 + ks) * 64 + lane) * 8);
            acc = __builtin_amdgcn_mfma_f32_16x16x32_bf16(al[ks], b, acc, 0, 0, 0);
            acc = __builtin_amdgcn_mfma_f32_16x16x32_bf16(ah[ks], b, acc, 0, 0, 0);
        }
        const float b1c = B1[ct * 16 + m];
        #pragma unroll
        for (int r = 0; r < 4; r++) {
            const float hv = fmaxf(acc[r] + b1c, 0.0f);
            h_s[(w * 16 + quad * 4 + r) * HPAD + ct * 16 + m] = f2bf(hv);
        }
    }

    f32x4 acc2[3];
    #pragma unroll
    for (int ct = 0; ct < 3; ct++) acc2[ct] = (f32x4){ 0.f, 0.f, 0.f, 0.f };
    #pragma unroll
    for (int ks = 0; ks < 8; ks++) {
        const bf16x8 a = *(const bf16x8*)&h_s[(w * 16 + m) * HPAD + ks * 32 + quad * 8];
        #pragma unroll
        for (int ct = 0; ct < 3; ct++) {
            const bf16x8 b = *(const bf16x8*)(pw2 + (size_t)((ct * 8 + ks) * 64 + lane) * 8);
            acc2[ct] = __builtin_amdgcn_mfma_f32_16x16x32_bf16(a, b, acc2[ct], 0, 0, 0);
        }
    }
    #pragma unroll
    for (int ct = 0; ct < 3; ct++) {
        const int cg = ct * 16 + m;
        const float b2c = (cg < NC) ? B2[cg] : 0.0f;
        #pragma unroll
        for (int r = 0; r < 4; r++)
            l_s[(w * 16 + quad * 4 + r) * LPAD + cg] = acc2[ct][r] + b2c;
    }
    __syncthreads();

    if (t < MT) {
        const int node = node0 + t;
        if (node < N) {
            const float* ln = &l_s[t * LPAD];
            float mx = -1e30f;
            #pragma unroll
            for (int c = 0; c < NC; c++) mx = fmaxf(mx, ln[c]);
            float s = 0.0f;
            #pragma unroll
            for (int c = 0; c < NC; c++) s += __expf(ln[c] - mx);
            const float lse = mx + __logf(s);
            float4* o = (float4*)(out + (size_t)node * NC);
            #pragma unroll
            for (int c4 = 0; c4 < NC / 4; c4++) {
                float4 v;
                v.x = ln[c4 * 4 + 0] - lse;
                v.y = ln[c4 * 4 + 1] - lse;
                v.z = ln[c4 * 4 + 2] - lse;
                v.w = ln[c4 * 4 + 3] - lse;
                o[c4] = v;
            }
        }
    }
}

extern "C" void kernel_launch(void* const* d_in, const int* in_sizes, int n_in,
                              void* d_out, int out_size, void* d_ws, size_t ws_size,
                              hipStream_t stream) {
    const float* feats = (const float*)d_in[0];
    const int* src = (const int*)d_in[1];
    const int* dst = (const int*)d_in[2];
    const float* W1 = (const float*)d_in[3];
    const float* B1 = (const float*)d_in[4];
    const float* W2 = (const float*)d_in[5];
    const float* B2 = (const float*)d_in[6];
    float* out = (float*)d_out;

    char* base = (char*)d_ws;
    size_t off = 0;
    auto alloc = [&](size_t bytes) -> void* {
        void* p = base + off;
        off += (bytes + 255) & ~(size_t)255;
        return p;
    };
    int*   deg    = (int*)  alloc((size_t)NN * 4);
    float* norm   = (float*)alloc((size_t)NN * 4);
    int*   rowptr = (int*)  alloc((size_t)(NN + 1) * 4);
    int*   cursor = (int*)  alloc((size_t)NN * 4);
    int*   bsum   = (int*)  alloc((size_t)SNB * 4);
    int*   boff   = (int*)  alloc((size_t)SNB * 4);
    int*   col    = (int*)  alloc((size_t)NE * 4);
    float* val    = (float*)alloc((size_t)NE * 4);
    u16*   pw1    = (u16*)  alloc((size_t)16 * 4 * 64 * 8 * 2);
    u16*   pw2    = (u16*)  alloc((size_t)3 * 8 * 64 * 8 * 2);
    u32*   xF     = (u32*)  alloc((size_t)NN * (IND / 2) * 4);  // bf16 feats
    u32*   xA     = (u32*)  alloc((size_t)NN * (IND / 2) * 4);
    u32*   xB     = (u32*)  alloc((size_t)NN * (IND / 2) * 4);
    float* yc     = (float*)alloc((size_t)NN * IND * 4);

    hipMemsetAsync(deg, 0, (size_t)NN * 4, stream);
    deg_i_k<<<(NE + 255) / 256, 256, 0, stream>>>(dst, deg, NE);
    norm_k<<<(NN + 255) / 256, 256, 0, stream>>>(deg, norm, NN);
    scan1_k<<<SNB, 256, 0, stream>>>(deg, bsum, NN);
    scan2_k<<<1, 128, 0, stream>>>(bsum, boff, rowptr, NN);
    scan3_k<<<SNB, 256, 0, stream>>>(deg, boff, rowptr, cursor, NN);
    fill_k<<<(NE + 255) / 256, 256, 0, stream>>>(src, dst, norm, cursor, col, val, NE);
    cvt_k<<<(NN * (IND / 2) + 255) / 256, 256, 0, stream>>>((const float2*)feats, xF,
                                                            NN * (IND / 2));
    pack_w1_k<<<(16 * 4 * 64 + 255) / 256, 256, 0, stream>>>(W1, pw1);
    pack_w2_k<<<(3 * 8 * 64 + 255) / 256, 256, 0, stream>>>(W2, pw2);

    const int sgrid = (NN * 64 + 255) / 256;
    spmm_k<1, 0><<<sgrid, 256, 0, stream>>>(xF, xA, yc, rowptr, col, val, NN);
    spmm_k<0, 0><<<sgrid, 256, 0, stream>>>(xA, xB, yc, rowptr, col, val, NN);
    spmm_k<0, 1><<<sgrid, 256, 0, stream>>>(xB, xA, yc, rowptr, col, val, NN);

    const int mgrid = (NN + MT - 1) / MT;
    mlp_mfma_k<<<mgrid, 256, 0, stream>>>(yc, pw1, B1, pw2, B2, out, NN);
}

// Round 8
// 342.726 us; speedup vs baseline: 11.5758x; 1.0507x over previous
//
#include <hip/hip_runtime.h>

#define NN 100000
#define NE 640000
#define IND 128
#define HD 256
#define NC 40
#define MT 64      // nodes per block in MLP
#define HPAD 264   // h_s row stride (bf16 elems)
#define LPAD 52    // l_s row stride (f32)
#define SCH 1024   // elements per scan block
#define SNB ((NN + SCH - 1) / SCH)   // 98 scan blocks

typedef unsigned short u16;
typedef unsigned int u32;
typedef __attribute__((ext_vector_type(8))) short bf16x8;
typedef __attribute__((ext_vector_type(4))) float f32x4;

__device__ __forceinline__ float bf2f(u16 u) {
    union { u32 i; float f; } c; c.i = ((u32)u) << 16; return c.f;
}
__device__ __forceinline__ u16 f2bf(float f) {
    union { float f; u32 i; } c; c.f = f;
    u32 i = c.i;
    return (u16)((i + 0x7FFFu + ((i >> 16) & 1u)) >> 16); // RNE
}

__global__ void deg_i_k(const int* __restrict__ dst, int* __restrict__ deg, int E) {
    int g = blockIdx.x * 256 + threadIdx.x;
    if (g < E) atomicAdd(&deg[dst[g]], 1);
}

// feats fp32 -> packed bf16x2
__global__ void cvt_k(const float2* __restrict__ f, u32* __restrict__ xb, int n) {
    int g = blockIdx.x * 256 + threadIdx.x;
    if (g >= n) return;
    float2 v = f[g];
    xb[g] = (u32)f2bf(v.x) | ((u32)f2bf(v.y) << 16);
}

// ---- hierarchical scan ----
__global__ __launch_bounds__(256) void scan1_k(const int* __restrict__ deg,
                                               int* __restrict__ bsum, int N) {
    __shared__ int s[256];
    const int t = threadIdx.x, b = blockIdx.x;
    const int base = b * SCH + t * 4;
    int acc = 0;
    #pragma unroll
    for (int j = 0; j < 4; j++) {
        int idx = base + j;
        if (idx < N) acc += deg[idx];
    }
    s[t] = acc;
    __syncthreads();
    for (int off = 128; off > 0; off >>= 1) {
        if (t < off) s[t] += s[t + off];
        __syncthreads();
    }
    if (t == 0) bsum[b] = s[0];
}

__global__ __launch_bounds__(128) void scan2_k(const int* __restrict__ bsum,
                                               int* __restrict__ boff,
                                               int* __restrict__ rowptr, int N) {
    __shared__ int s[128];
    const int t = threadIdx.x;
    const int own = (t < SNB) ? bsum[t] : 0;
    s[t] = own;
    __syncthreads();
    #pragma unroll
    for (int off = 1; off < 128; off <<= 1) {
        int v = (t >= off) ? s[t - off] : 0;
        __syncthreads();
        s[t] += v;
        __syncthreads();
    }
    if (t < SNB) boff[t] = s[t] - own;
    if (t == 127) rowptr[N] = s[127];
}

// pass3: rowptr & cursor; also folds norm = rsqrt(max(deg,1))
__global__ __launch_bounds__(256) void scan3_k(const int* __restrict__ deg,
                                               const int* __restrict__ boff,
                                               int* __restrict__ rowptr,
                                               int* __restrict__ cursor,
                                               float* __restrict__ norm, int N) {
    __shared__ int s[256];
    const int t = threadIdx.x, b = blockIdx.x;
    const int base = b * SCH + t * 4;
    int d4[4]; int own = 0;
    #pragma unroll
    for (int j = 0; j < 4; j++) {
        int idx = base + j;
        d4[j] = (idx < N) ? deg[idx] : 0;
        own += d4[j];
    }
    s[t] = own;
    __syncthreads();
    #pragma unroll
    for (int off = 1; off < 256; off <<= 1) {
        int v = (t >= off) ? s[t - off] : 0;
        __syncthreads();
        s[t] += v;
        __syncthreads();
    }
    int run = boff[b] + s[t] - own;
    #pragma unroll
    for (int j = 0; j < 4; j++) {
        int idx = base + j;
        if (idx < N) {
            rowptr[idx] = run; cursor[idx] = run; run += d4[j];
            norm[idx] = rsqrtf(fmaxf((float)d4[j], 1.0f));
        }
    }
}

// CSR fill: cv = {src, bits(norm[src]*norm[dst])}
__global__ void fill_k(const int* __restrict__ src, const int* __restrict__ dst,
                       const float* __restrict__ norm, int* __restrict__ cursor,
                       int2* __restrict__ cv, int E) {
    int e = blockIdx.x * 256 + threadIdx.x;
    if (e >= E) return;
    int s = src[e], d = dst[e];
    int pos = atomicAdd(&cursor[d], 1);
    cv[pos] = make_int2(s, __float_as_int(norm[s] * norm[d]));
}

// gather-SpMM, one wave per dst row, bf16 x, 2 feats/lane, 8-edge ILP batches.
// LAST: fuse final y: ysum = 0.25*(x0 + x1 + x2 + a3) -> bf16 (pre-scaled for MLP).
template <int LAST>
__global__ __launch_bounds__(256) void spmm_k(
    const u32* __restrict__ x, u32* __restrict__ xnext,
    const u32* __restrict__ x0, const u32* __restrict__ x1,
    const int2* __restrict__ cv, const int* __restrict__ rowptr, int N)
{
    const int wid = (blockIdx.x * 256 + threadIdx.x) >> 6;
    const int lane = threadIdx.x & 63;
    if (wid >= N) return;
    const int beg = rowptr[wid], end = rowptr[wid + 1];
    float a0 = 0.0f, a1 = 0.0f;
    if (beg < end) {
        for (int e = beg; e < end; e += 8) {
            int2 c8[8]; u32 u8[8];
            #pragma unroll
            for (int j = 0; j < 8; j++) {
                const int ee = e + j;
                c8[j] = cv[ee < end ? ee : end - 1];
                if (ee >= end) c8[j].y = 0;  // w = 0.0f
            }
            #pragma unroll
            for (int j = 0; j < 8; j++)
                u8[j] = x[(size_t)c8[j].x * (IND / 2) + lane];
            #pragma unroll
            for (int j = 0; j < 8; j++) {
                const float w = __int_as_float(c8[j].y);
                a0 = fmaf(bf2f((u16)(u8[j] & 0xFFFFu)), w, a0);
                a1 = fmaf(bf2f((u16)(u8[j] >> 16)),     w, a1);
            }
        }
    }
    const size_t ri = (size_t)wid * (IND / 2) + lane;
    if (!LAST) {
        xnext[ri] = (u32)f2bf(a0) | ((u32)f2bf(a1) << 16);
    } else {
        const u32 v0 = x0[ri], v1 = x1[ri], v2 = x[ri];
        const float s0 = bf2f((u16)(v0 & 0xFFFFu)) + bf2f((u16)(v1 & 0xFFFFu))
                       + bf2f((u16)(v2 & 0xFFFFu)) + a0;
        const float s1 = bf2f((u16)(v0 >> 16)) + bf2f((u16)(v1 >> 16))
                       + bf2f((u16)(v2 >> 16)) + a1;
        xnext[ri] = (u32)f2bf(s0 * 0.25f) | ((u32)f2bf(s1 * 0.25f) << 16);
    }
}

// Pack W1 [128x256] -> [ct(16)][ks(4)][lane(64)][j(8)]; W2 [256x40] -> [ct(3)][ks(8)][lane(64)][j(8)]
__global__ void pack_w_k(const float* __restrict__ W1, const float* __restrict__ W2,
                         u16* __restrict__ pw1, u16* __restrict__ pw2) {
    const int b = blockIdx.x, t = threadIdx.x;
    if (b < 16) {
        int idx = b * 256 + t;
        int lane = idx & 63, fid = idx >> 6;
        int ks = fid & 3, ct = fid >> 2;
        int quad = lane >> 4, m = lane & 15;
        int n = ct * 16 + m;
        u16* o = pw1 + (size_t)idx * 8;
        #pragma unroll
        for (int j = 0; j < 8; j++) {
            int k = ks * 32 + quad * 8 + j;
            o[j] = f2bf(W1[k * HD + n]);
        }
    } else {
        int idx = (b - 16) * 256 + t;
        if (idx >= 3 * 8 * 64) return;
        int lane = idx & 63, fid = idx >> 6;
        int ks = fid & 7, ct = fid >> 3;
        int quad = lane >> 4, m = lane & 15;
        int n = ct * 16 + m;
        u16* o = pw2 + (size_t)idx * 8;
        #pragma unroll
        for (int j = 0; j < 8; j++) {
            int k = ks * 32 + quad * 8 + j;
            o[j] = (n < NC) ? f2bf(W2[k * NC + n]) : (u16)0;
        }
    }
}

// MFMA MLP: 64 nodes/block, 4 waves x 16-node tiles.
// A = ysum rows loaded directly as bf16 fragments (pre-scaled by 0.25 in spmm<LAST>).
__global__ __launch_bounds__(256) void mlp_mfma_k(
    const u16* __restrict__ ys, const u16* __restrict__ pw1,
    const float* __restrict__ B1, const u16* __restrict__ pw2,
    const float* __restrict__ B2, float* __restrict__ out, int N)
{
    __shared__ u16 h_s[MT * HPAD];
    __shared__ float l_s[MT * LPAD];
    const int t = threadIdx.x;
    const int w = t >> 6, lane = t & 63;
    const int quad = lane >> 4, m = lane & 15;
    const int node0 = blockIdx.x * MT;

    int nodeA = node0 + w * 16 + m;
    if (nodeA > N - 1) nodeA = N - 1;
    bf16x8 av[4];
    #pragma unroll
    for (int ks = 0; ks < 4; ks++)
        av[ks] = *(const bf16x8*)(ys + (size_t)nodeA * IND + ks * 32 + quad * 8);

    #pragma unroll 4
    for (int ct = 0; ct < 16; ct++) {
        f32x4 acc = { 0.f, 0.f, 0.f, 0.f };
        #pragma unroll
        for (int ks = 0; ks < 4; ks++) {
            const bf16x8 b = *(const bf16x8*)(pw1 + (size_t)((ct * 4 + ks) * 64 + lane) * 8);
            acc = __builtin_amdgcn_mfma_f32_16x16x32_bf16(av[ks], b, acc, 0, 0, 0);
        }
        const float b1c = B1[ct * 16 + m];
        #pragma unroll
        for (int r = 0; r < 4; r++) {
            const float hv = fmaxf(acc[r] + b1c, 0.0f);
            h_s[(w * 16 + quad * 4 + r) * HPAD + ct * 16 + m] = f2bf(hv);
        }
    }

    f32x4 acc2[3];
    #pragma unroll
    for (int ct = 0; ct < 3; ct++) acc2[ct] = (f32x4){ 0.f, 0.f, 0.f, 0.f };
    #pragma unroll
    for (int ks = 0; ks < 8; ks++) {
        const bf16x8 a = *(const bf16x8*)&h_s[(w * 16 + m) * HPAD + ks * 32 + quad * 8];
        #pragma unroll
        for (int ct = 0; ct < 3; ct++) {
            const bf16x8 b = *(const bf16x8*)(pw2 + (size_t)((ct * 8 + ks) * 64 + lane) * 8);
            acc2[ct] = __builtin_amdgcn_mfma_f32_16x16x32_bf16(a, b, acc2[ct], 0, 0, 0);
        }
    }
    #pragma unroll
    for (int ct = 0; ct < 3; ct++) {
        const int cg = ct * 16 + m;
        const float b2c = (cg < NC) ? B2[cg] : 0.0f;
        #pragma unroll
        for (int r = 0; r < 4; r++)
            l_s[(w * 16 + quad * 4 + r) * LPAD + cg] = acc2[ct][r] + b2c;
    }
    __syncthreads();

    if (t < MT) {
        const int node = node0 + t;
        if (node < N) {
            const float* ln = &l_s[t * LPAD];
            float mx = -1e30f;
            #pragma unroll
            for (int c = 0; c < NC; c++) mx = fmaxf(mx, ln[c]);
            float s = 0.0f;
            #pragma unroll
            for (int c = 0; c < NC; c++) s += __expf(ln[c] - mx);
            const float lse = mx + __logf(s);
            float4* o = (float4*)(out + (size_t)node * NC);
            #pragma unroll
            for (int c4 = 0; c4 < NC / 4; c4++) {
                float4 v;
                v.x = ln[c4 * 4 + 0] - lse;
                v.y = ln[c4 * 4 + 1] - lse;
                v.z = ln[c4 * 4 + 2] - lse;
                v.w = ln[c4 * 4 + 3] - lse;
                o[c4] = v;
            }
        }
    }
}

extern "C" void kernel_launch(void* const* d_in, const int* in_sizes, int n_in,
                              void* d_out, int out_size, void* d_ws, size_t ws_size,
                              hipStream_t stream) {
    const float* feats = (const float*)d_in[0];
    const int* src = (const int*)d_in[1];
    const int* dst = (const int*)d_in[2];
    const float* W1 = (const float*)d_in[3];
    const float* B1 = (const float*)d_in[4];
    const float* W2 = (const float*)d_in[5];
    const float* B2 = (const float*)d_in[6];
    float* out = (float*)d_out;

    char* base = (char*)d_ws;
    size_t off = 0;
    auto alloc = [&](size_t bytes) -> void* {
        void* p = base + off;
        off += (bytes + 255) & ~(size_t)255;
        return p;
    };
    int*   deg    = (int*)  alloc((size_t)NN * 4);
    float* norm   = (float*)alloc((size_t)NN * 4);
    int*   rowptr = (int*)  alloc((size_t)(NN + 1) * 4);
    int*   cursor = (int*)  alloc((size_t)NN * 4);
    int*   bsum   = (int*)  alloc((size_t)SNB * 4);
    int*   boff   = (int*)  alloc((size_t)SNB * 4);
    int2*  cv     = (int2*) alloc((size_t)NE * 8);
    u16*   pw1    = (u16*)  alloc((size_t)16 * 4 * 64 * 8 * 2);
    u16*   pw2    = (u16*)  alloc((size_t)3 * 8 * 64 * 8 * 2);
    u32*   xF     = (u32*)  alloc((size_t)NN * (IND / 2) * 4);  // bf16 feats (x0)
    u32*   xA     = (u32*)  alloc((size_t)NN * (IND / 2) * 4);  // x1
    u32*   xB     = (u32*)  alloc((size_t)NN * (IND / 2) * 4);  // x2
    u32*   ys     = (u32*)  alloc((size_t)NN * (IND / 2) * 4);  // 0.25*(x0+x1+x2+x3)

    hipMemsetAsync(deg, 0, (size_t)NN * 4, stream);
    deg_i_k<<<(NE + 255) / 256, 256, 0, stream>>>(dst, deg, NE);
    scan1_k<<<SNB, 256, 0, stream>>>(deg, bsum, NN);
    scan2_k<<<1, 128, 0, stream>>>(bsum, boff, rowptr, NN);
    scan3_k<<<SNB, 256, 0, stream>>>(deg, boff, rowptr, cursor, norm, NN);
    fill_k<<<(NE + 255) / 256, 256, 0, stream>>>(src, dst, norm, cursor, cv, NE);
    cvt_k<<<(NN * (IND / 2) + 255) / 256, 256, 0, stream>>>((const float2*)feats, xF,
                                                            NN * (IND / 2));
    pack_w_k<<<22, 256, 0, stream>>>(W1, W2, pw1, pw2);

    const int sgrid = (NN * 64 + 255) / 256;
    spmm_k<0><<<sgrid, 256, 0, stream>>>(xF, xA, nullptr, nullptr, cv, rowptr, NN);
    spmm_k<0><<<sgrid, 256, 0, stream>>>(xA, xB, nullptr, nullptr, cv, rowptr, NN);
    spmm_k<1><<<sgrid, 256, 0, stream>>>(xB, ys, xF, xA, cv, rowptr, NN);

    const int mgrid = (NN + MT - 1) / MT;
    mlp_mfma_k<<<mgrid, 256, 0, stream>>>((const u16*)ys, pw1, B1, pw2, B2, out, NN);
}